// Round 7
// baseline (392.681 us; speedup 1.0000x reference)
//
#include <hip/hip_runtime.h>
#include <cstdint>
#include <cstddef>

// Problem constants (B,S,E,H)=(2,2048,2048,16), D=128, RD=128 (full-rotary)
#define Bd 2
#define Sd 2048
#define Ed 2048
#define Hd 16
#define Dd 128
#define N3E 6144
#define ATT_SCALE 0.08838834764831845f   // 1/sqrt(128)

typedef short bf16x8 __attribute__((ext_vector_type(8)));
typedef float f32x4 __attribute__((ext_vector_type(4)));
typedef float f32x16 __attribute__((ext_vector_type(16)));

__device__ __forceinline__ float bf2f(unsigned short u) {
    union { unsigned int u; float f; } c;
    c.u = ((unsigned int)u) << 16;
    return c.f;
}
__device__ __forceinline__ unsigned short f2bf(float f) {
    union { float f; unsigned int u; } c;
    c.f = f;
    unsigned int x = c.u;
    x += 0x7FFFu + ((x >> 16) & 1u);   // RTNE (finite values only)
    return (unsigned short)(x >> 16);
}

__device__ __forceinline__ void gl2lds16(const void* g, void* l) {
    __builtin_amdgcn_global_load_lds(
        (const __attribute__((address_space(1))) void*)g,
        (__attribute__((address_space(3))) void*)l, 16, 0, 0);
}

__device__ __forceinline__ void gatomic_fadd(float* p, float v) {
#if __has_builtin(__builtin_amdgcn_global_atomic_fadd_f32)
    (void)__builtin_amdgcn_global_atomic_fadd_f32(
        (__attribute__((address_space(1))) float*)p, v);
#else
    atomicAdd(p, v);
#endif
}

// ---- fp32 -> bf16 convert (x, wqkv_w, out_w) + d_out bias-init, one launch --
__global__ void cvt_all(const float* __restrict__ x,
                        const float* __restrict__ w1,
                        const float* __restrict__ w2,
                        const float* __restrict__ ob,
                        unsigned short* __restrict__ ox,
                        unsigned short* __restrict__ o1,
                        unsigned short* __restrict__ o2,
                        float* __restrict__ oinit) {
    int i = (blockIdx.x * 256 + threadIdx.x) * 4;
    if (i < 25165824) {
        const float* s;
        unsigned short* d;
        int off;
        if (i < 8388608) { s = x; d = ox; off = i; }
        else if (i < 20971520) { s = w1; d = o1; off = i - 8388608; }
        else { s = w2; d = o2; off = i - 20971520; }
        const float4 v = *(const float4*)(s + off);
        d[off + 0] = f2bf(v.x);
        d[off + 1] = f2bf(v.y);
        d[off + 2] = f2bf(v.z);
        d[off + 3] = f2bf(v.w);
    } else {
        // init d_out rows with out_b (split-K gemm atomically accumulates on top)
        int off = i - 25165824;          // 0..8388607; out[r*2048 + c]
        int c = off & 2047;              // 2048 % 4 == 0 -> c..c+3 in one row
        float4 bv;
        bv.x = ob[c + 0];
        bv.y = ob[c + 1];
        bv.z = ob[c + 2];
        bv.w = ob[c + 3];
        *(float4*)(oinit + off) = bv;
    }
}

// ---------------- bf16 MFMA GEMM, C = A * B^T + bias ----------------
// A: M x K (K contig), Bm: N x K (K contig). 128x128 tile, BK=64, 4 waves (2x2 of 64x64).
// XOR-swizzled LDS (8 chunks/row of 16B) so frag ds_read_b128 is 2-way (free).
// MODE 1: fused QKV epilogue. Each 128-col tile = one head (D=128) of q/k/v:
//   tile -> LDS (bf16, stride 130), then q/k: RoPE + store [B,H,S,D];
//   v: transpose via column gather -> [B,H,D,S].
// MODE 2: split-K (blockIdx.z halves K), fp32 atomic-accumulate into o0
//   (pre-initialized with bias by cvt_all; stream order guarantees init first).
template <int MODE>
__global__ void gemm_bt(const unsigned short* __restrict__ A,
                        const unsigned short* __restrict__ Bm,
                        const float* __restrict__ bias,
                        void* __restrict__ o0, void* __restrict__ o1,
                        void* __restrict__ o2, int Ndim, int K) {
    // union: staging (As 16KB + Bs 16KB) / epilogue tile 128x130 bf16 (33,280B)
    __shared__ __align__(16) unsigned short U[16640];
    unsigned short* As = U;
    unsigned short* Bs = U + 8192;

    const int tid = threadIdx.x;
    const int lane = tid & 63;
    const int wave = tid >> 6;
    const int quad = lane >> 4;
    const int l16 = lane & 15;
    const int wr = wave >> 1;
    const int wc = wave & 1;

    const int n0 = blockIdx.x * 128;
    const int m0 = blockIdx.y * 128;

    const unsigned short* Ab = A + (size_t)m0 * K;
    const unsigned short* Bb = Bm + (size_t)n0 * K;

    const f32x4 fzero = {0.f, 0.f, 0.f, 0.f};
    f32x4 acc[4][4];
#pragma unroll
    for (int i = 0; i < 4; i++)
#pragma unroll
        for (int j = 0; j < 4; j++) acc[i][j] = fzero;

    const int kbase = (MODE == 2) ? blockIdx.z * (K >> 1) : 0;
    const int kend = (MODE == 2) ? kbase + (K >> 1) : K;
    for (int k0 = kbase; k0 < kend; k0 += 64) {
        __syncthreads();
#pragma unroll
        for (int it = 0; it < 4; ++it) {
            int L = it * 256 + tid;
            int row = L >> 3;
            int cs = L & 7;
            int gc = cs ^ (row & 7);
            gl2lds16(Ab + row * K + k0 + gc * 8, (void*)(As + L * 8));
            gl2lds16(Bb + row * K + k0 + gc * 8, (void*)(Bs + L * 8));
        }
        __syncthreads();
#pragma unroll
        for (int kk = 0; kk < 2; ++kk) {
            bf16x8 af[4], bfr[4];
#pragma unroll
            for (int i = 0; i < 4; i++) {
                int row = wr * 64 + i * 16 + l16;
                int cs = kk * 4 + quad;
                af[i] = *(const bf16x8*)(As + row * 64 + (cs ^ (row & 7)) * 8);
            }
#pragma unroll
            for (int j = 0; j < 4; j++) {
                int row = wc * 64 + j * 16 + l16;
                int cs = kk * 4 + quad;
                bfr[j] = *(const bf16x8*)(Bs + row * 64 + (cs ^ (row & 7)) * 8);
            }
#pragma unroll
            for (int i = 0; i < 4; i++)
#pragma unroll
                for (int j = 0; j < 4; j++)
                    acc[i][j] = __builtin_amdgcn_mfma_f32_16x16x32_bf16(
                        af[i], bfr[j], acc[i][j], 0, 0, 0);
        }
    }

    if (MODE == 2) {
#pragma unroll
        for (int j = 0; j < 4; j++) {
            int col = n0 + wc * 64 + j * 16 + l16;
#pragma unroll
            for (int i = 0; i < 4; i++) {
                int rbase = m0 + wr * 64 + i * 16 + quad * 4;
#pragma unroll
                for (int r = 0; r < 4; r++)
                    gatomic_fadd((float*)o0 + (size_t)(rbase + r) * Ndim + col,
                                 acc[i][j][r]);
            }
        }
    } else {
        // ---- fused QKV epilogue ----
        __syncthreads();  // all frag reads of As/Bs done before tile overwrite
#pragma unroll
        for (int j = 0; j < 4; j++) {
            int coll = wc * 64 + j * 16 + l16;   // tile-local col = d
            float bv = bias[n0 + coll];
#pragma unroll
            for (int i = 0; i < 4; i++) {
                int rl = wr * 64 + i * 16 + quad * 4;
#pragma unroll
                for (int r = 0; r < 4; r++)
                    U[(rl + r) * 130 + coll] = f2bf(acc[i][j][r] + bv);
            }
        }
        __syncthreads();

        const int ch = n0 >> 7;         // 0..47
        const int c = ch >> 4;          // 0=q 1=k 2=v
        const int h = ch & 15;
        const int bb = m0 >> 11;        // batch (tile never crosses: 2048%128==0)
        const int s0 = m0 & 2047;

        if (c < 2) {
            unsigned short* dstq = (unsigned short*)(c == 0 ? o0 : o1);
            const size_t hb = ((size_t)(bb * Hd + h)) * Sd;
#pragma unroll
            for (int it = 0; it < 16; ++it) {
                int lin = it * 256 + tid;        // 128 rows x 32 d-pairs
                int row = lin >> 5, p = lin & 31;
                int s = s0 + row;
                unsigned int lo = *(const unsigned int*)(U + row * 130 + 2 * p);
                unsigned int hi =
                    *(const unsigned int*)(U + row * 130 + 64 + 2 * p);
                float v1a = bf2f((unsigned short)lo), v1b = bf2f(lo >> 16);
                float v2a = bf2f((unsigned short)hi), v2b = bf2f(hi >> 16);
                // theta_j = s * 10000^(-j/64),  j = 2p, 2p+1
                float fa = (float)s * __expf(-(float)(2 * p) *
                                             (9.210340371976184f / 64.0f));
                float fb = (float)s * __expf(-(float)(2 * p + 1) *
                                             (9.210340371976184f / 64.0f));
                float sna, csa, snb, csb;
                __sincosf(fa, &sna, &csa);
                __sincosf(fb, &snb, &csb);
                ushort2 r1, r2;
                r1.x = f2bf(v1a * csa - v2a * sna);
                r1.y = f2bf(v1b * csb - v2b * snb);
                r2.x = f2bf(v1a * sna + v2a * csa);
                r2.y = f2bf(v1b * snb + v2b * csb);
                unsigned short* dst = dstq + (hb + s) * Dd;
                *(ushort2*)(dst + 2 * p) = r1;
                *(ushort2*)(dst + 64 + 2 * p) = r2;
            }
        } else {
            unsigned short* dstv = (unsigned short*)o2;
            const size_t hb = ((size_t)(bb * Hd + h)) * Dd;
#pragma unroll
            for (int it = 0; it < 16; ++it) {
                int lin = it * 256 + tid;        // 128 d x 32 s-chunks
                int d = lin >> 5, sc = lin & 31;
                int s4 = sc * 4;
                ushort4 pk;
                pk.x = U[(s4 + 0) * 130 + d];
                pk.y = U[(s4 + 1) * 130 + d];
                pk.z = U[(s4 + 2) * 130 + d];
                pk.w = U[(s4 + 3) * 130 + d];
                *(ushort4*)(dstv + (hb + d) * Sd + s0 + s4) = pk;
            }
        }
    }
}

// ---------------- flash attention (causal, online softmax) ----------------
// 32x32x16 MFMA, BM=128 (32 q/wave), BN=64. S^T = K*Q^T with Q in registers;
// O^T = Vt*P^T. C/D col = q = lane&31 -> softmax and alpha/li rescale fully
// lane-local (1 shfl_xor per reduction). Ps is 128x64 with XOR-chunk swizzle
// so every ds access is naturally aligned (stride-68 variant had misaligned
// ds_read_b128 = UB -> nondeterministic replays).
// 32x32 layouts (verified): A/B [n=lane&31][k=(lane>>5)*8+j];
// C/D col=lane&31, row=(reg&3)+8*(reg>>2)+4*(lane>>5).
__global__ __launch_bounds__(256, 2) void flash_attn(
    const unsigned short* __restrict__ q, const unsigned short* __restrict__ k,
    const unsigned short* __restrict__ vt, unsigned short* __restrict__ ctx) {
    __shared__ __align__(16) unsigned short Ks[64 * 128];   // 16 KB [t][d], 16 chunks/row, xor row&15
    __shared__ __align__(16) unsigned short Vts[128 * 64];  // 16 KB [d][t], 8 chunks/row, xor row&7
    __shared__ __align__(16) unsigned short Ps[128 * 64];   // 16 KB [q][t], 8 chunks/row, xor row&7

    const int tid = threadIdx.x;
    const int lane = tid & 63;
    const int wave = tid >> 6;
    const int l32 = lane & 31;
    const int half = lane >> 5;

    // qi pairing: CU gets blocks y and y+8 (round-robin, 512 blocks / 256 CU)
    // -> qi {15-y, y}: per-CU tile count constant (34).
    const int yy = blockIdx.y;
    const int qi = (yy < 8) ? 15 - yy : yy - 8;
    const int bh = blockIdx.x;
    const int q0 = qi * 128;
    const int qg = q0 + wave * 32 + l32;        // this lane's global q row
    const int prow = wave * 32 + l32;           // P row (q local)
    const int psw = prow & 7;                   // P swizzle key

    const unsigned short* kb = k + (size_t)bh * Sd * Dd;
    const unsigned short* vtb = vt + (size_t)bh * Dd * Sd;

    // Q fragments straight from global: lane owns row qg, frag ks covers
    // d = ks*16 + half*8 + {0..7}  (B-operand layout), 8 x 16B loads.
    bf16x8 aq[8];
    {
        const unsigned short* qrow = q + ((size_t)bh * Sd + qg) * Dd;
#pragma unroll
        for (int ks = 0; ks < 8; ks++)
            aq[ks] = *(const bf16x8*)(qrow + ks * 16 + half * 8);
    }

    f32x16 o[4];   // O^T: d-block db: row d = db*32+(r&3)+8*(r>>2)+4*half, col q=l32
#pragma unroll
    for (int db = 0; db < 4; db++)
#pragma unroll
        for (int r = 0; r < 16; r++) o[db][r] = 0.f;
    float mi = -3.0e38f, li = 0.f;

    const int tmax = q0 + 64;
    for (int t0 = 0; t0 <= tmax; t0 += 64) {
        // stage K [64t][128d] and Vt [128d][64t], 1024 16B-chunks each
#pragma unroll
        for (int it = 0; it < 4; ++it) {
            int L = it * 256 + tid;
            int rk = L >> 4;
            int ck = L & 15;
            int gk = ck ^ (rk & 15);
            gl2lds16(kb + (size_t)(t0 + rk) * Dd + gk * 8, (void*)(Ks + L * 8));
            int rv = L >> 3;
            int cv = L & 7;
            int gv = cv ^ (rv & 7);
            gl2lds16(vtb + (size_t)rv * Sd + t0 + gv * 8, (void*)(Vts + L * 8));
        }
        __syncthreads();

        // S^T = K * Q^T : 2 t-blocks of 32, contraction d=128 (8 ksteps)
        f32x16 sa[2];
#pragma unroll
        for (int b2 = 0; b2 < 2; b2++)
#pragma unroll
            for (int r = 0; r < 16; r++) sa[b2][r] = 0.f;
#pragma unroll
        for (int ks = 0; ks < 8; ks++) {
            int cd = ks * 2 + half;
#pragma unroll
            for (int b2 = 0; b2 < 2; b2++) {
                int row = b2 * 32 + l32;
                bf16x8 ak = *(const bf16x8*)(Ks + row * 128 +
                                             (cd ^ (row & 15)) * 8);
                sa[b2] = __builtin_amdgcn_mfma_f32_32x32x16_bf16(ak, aq[ks],
                                                                 sa[b2], 0, 0, 0);
            }
        }

        // scale + causal mask; per-lane row max over 32 reg values + 1 shfl
        float mx = -3.0e38f;
#pragma unroll
        for (int b2 = 0; b2 < 2; b2++)
#pragma unroll
            for (int r = 0; r < 16; r++) {
                float v = sa[b2][r] * ATT_SCALE;
                int tg = t0 + b2 * 32 + (r & 3) + 8 * (r >> 2) + 4 * half;
                if (tg > qg) v = -3.0e38f;
                sa[b2][r] = v;
                mx = fmaxf(mx, v);
            }
        mx = fmaxf(mx, __shfl_xor(mx, 32, 64));
        const float mnew = fmaxf(mi, mx);
        const float alpha = __expf(mi - mnew);
        float rs = 0.f;
#pragma unroll
        for (int b2 = 0; b2 < 2; b2++)
#pragma unroll
            for (int r = 0; r < 16; r++) {
                float pp = __expf(sa[b2][r] - mnew);
                sa[b2][r] = pp;
                rs += pp;
            }
        rs += __shfl_xor(rs, 32, 64);
        li = li * alpha + rs;
        mi = mnew;

        // rescale O (fully in-lane: O^T col q == softmax lane q)
#pragma unroll
        for (int db = 0; db < 4; db++)
#pragma unroll
            for (int r = 0; r < 16; r++) o[db][r] *= alpha;

        // P store: row prow holds P[q][t] in t-order, 8 chunks of 8 ushorts,
        // chunk XOR-swizzled by prow&7. reg (b2,g) -> t = b2*32+8g+4*half+{0..3}
        // -> chunk b2*4+g, within-chunk half*4: 8B-aligned ds_write_b64.
#pragma unroll
        for (int b2 = 0; b2 < 2; b2++)
#pragma unroll
            for (int g = 0; g < 4; g++) {
                ushort4 pk;
                pk.x = f2bf(sa[b2][g * 4 + 0]);
                pk.y = f2bf(sa[b2][g * 4 + 1]);
                pk.z = f2bf(sa[b2][g * 4 + 2]);
                pk.w = f2bf(sa[b2][g * 4 + 3]);
                *(ushort4*)(Ps + prow * 64 + ((b2 * 4 + g) ^ psw) * 8 +
                            half * 4) = pk;
            }
        __syncthreads();  // P visible (and guards vs any cross-lane timing)

        // O^T += Vt * P^T : 4 d-blocks, contraction t=64 (4 ksteps)
        // bp chunk = kk*2+half -> t = kk*16+half*8+{0..7}: 16B-aligned b128.
#pragma unroll
        for (int kk = 0; kk < 4; kk++) {
            bf16x8 bp = *(const bf16x8*)(Ps + prow * 64 +
                                         ((kk * 2 + half) ^ psw) * 8);
#pragma unroll
            for (int db = 0; db < 4; db++) {
                int row = db * 32 + l32;
                bf16x8 av = *(const bf16x8*)(
                    Vts + row * 64 + ((kk * 2 + half) ^ (row & 7)) * 8);
                o[db] = __builtin_amdgcn_mfma_f32_32x32x16_bf16(av, bp, o[db],
                                                                0, 0, 0);
            }
        }
        __syncthreads();  // protect Ks/Vts/Ps before next-tile staging
    }

    // epilogue: ctx[b, qg, h*128+d] = O^T[d][qg] / li  (bf16, ushort4 groups)
    const int b = bh >> 4;
    const int h = bh & 15;
    const float inv = 1.0f / li;
    unsigned short* dst = ctx + ((size_t)(b * Sd + qg)) * Ed + h * Dd;
#pragma unroll
    for (int db = 0; db < 4; db++)
#pragma unroll
        for (int g = 0; g < 4; g++) {
            ushort4 pk;
            pk.x = f2bf(o[db][g * 4 + 0] * inv);
            pk.y = f2bf(o[db][g * 4 + 1] * inv);
            pk.z = f2bf(o[db][g * 4 + 2] * inv);
            pk.w = f2bf(o[db][g * 4 + 3] * inv);
            *(ushort4*)(dst + db * 32 + g * 8 + half * 4) = pk;
        }
}

extern "C" void kernel_launch(void* const* d_in, const int* in_sizes, int n_in,
                              void* d_out, int out_size, void* d_ws,
                              size_t ws_size, hipStream_t stream) {
    const float* x = (const float*)d_in[0];
    const float* wqkv_w = (const float*)d_in[1];
    const float* wqkv_b = (const float*)d_in[2];
    const float* out_w = (const float*)d_in[3];
    const float* out_b = (const float*)d_in[4];
    float* out = (float*)d_out;

    // workspace layout (bytes); total 100,663,296 (96 MiB)
    char* ws = (char*)d_ws;
    unsigned short* xb    = (unsigned short*)(ws + 0);         // 16 MiB, dead after QKV GEMM
    unsigned short* wqkvb = (unsigned short*)(ws + 16777216);  // 24 MiB
    unsigned short* owb   = (unsigned short*)(ws + 41943040);  // 8 MiB
    unsigned short* qb    = (unsigned short*)(ws + 50331648);  // 16 MiB [B,H,S,D]
    unsigned short* kb    = (unsigned short*)(ws + 67108864);  // 16 MiB [B,H,S,D]
    unsigned short* vtb   = (unsigned short*)(ws + 83886080);  // 16 MiB [B,H,D,S]
    unsigned short* ctx   = (unsigned short*)(ws + 0);         // alias xb (dead)

    // converts + d_out := bias (out-gemm atomically accumulates on top)
    cvt_all<<<32768, 256, 0, stream>>>(x, wqkv_w, out_w, out_b, xb, wqkvb, owb,
                                       out);
    // qkv = x @ wqkv_w^T + b, fused RoPE (q,k) + V-transpose in epilogue
    gemm_bt<1><<<dim3(48, 32), 256, 0, stream>>>(xb, wqkvb, wqkv_b, qb, kb, vtb,
                                                 N3E, Ed);
    flash_attn<<<dim3(32, 16), 256, 0, stream>>>(qb, kb, vtb, ctx);
    // out += ctx @ out_w^T  (split-K=2, fp32 atomic accumulate)
    gemm_bt<2><<<dim3(16, 32, 2), 256, 0, stream>>>(ctx, owb, out_b, out,
                                                    nullptr, nullptr, Ed, Ed);
}